// Round 4
// baseline (335.673 us; speedup 1.0000x reference)
//
#include <hip/hip_runtime.h>
#include <hip/hip_bf16.h>
#include <stdint.h>

#define BB 2048
#define UU 1024
#define SKIPN 24

typedef __attribute__((ext_vector_type(8))) short short8;
typedef __attribute__((ext_vector_type(4))) float f32x4;
typedef __attribute__((ext_vector_type(4))) unsigned short ushort4_t;

static __device__ __forceinline__ float sigmoidf_(float x) {
    return 1.0f / (1.0f + __expf(-x));
}

static __device__ __forceinline__ void load_lds16(const void* g, void* l) {
    __builtin_amdgcn_global_load_lds((const __attribute__((address_space(1))) void*)g,
                                     (__attribute__((address_space(3))) void*)l, 16, 0, 0);
}

// ---------------- prep: weight transpose->bf16 + activation convert->bf16 -------
__global__ __launch_bounds__(256) void prep(
    const float* __restrict__ inputs, const float* __restrict__ h_tm1,
    const float* __restrict__ prev_h, const float* __restrict__ kernel,
    const float* __restrict__ rkernel, const float* __restrict__ kernel2,
    __hip_bfloat16* __restrict__ kt, __hip_bfloat16* __restrict__ rkt,
    __hip_bfloat16* __restrict__ k2t, __hip_bfloat16* __restrict__ xin,
    __hip_bfloat16* __restrict__ hb, __hip_bfloat16* __restrict__ ph0) {
    const int bid = blockIdx.x;
    if (bid < 9216) {
        __shared__ float tile[32][33];
        const float* src;
        __hip_bfloat16* dst;
        int C, local;
        if (bid < 4096)      { src = kernel;  dst = kt;  C = 4096; local = bid; }
        else if (bid < 8192) { src = rkernel; dst = rkt; C = 4096; local = bid - 4096; }
        else                 { src = kernel2; dst = k2t; C = 1024; local = bid - 8192; }
        const int xt = (C == 4096) ? 128 : 32;
        const int bc = (local % xt) * 32;
        const int br = (local / xt) * 32;
        const int tx = threadIdx.x & 31, ty = threadIdx.x >> 5;
#pragma unroll
        for (int i = 0; i < 32; i += 8)
            tile[ty + i][tx] = src[(size_t)(br + ty + i) * C + bc + tx];
        __syncthreads();
#pragma unroll
        for (int i = 0; i < 32; i += 8)
            dst[(size_t)(bc + ty + i) * 1024 + br + tx] = __float2bfloat16(tile[tx][ty + i]);
    } else {
        const int idx = (bid - 9216) * 256 + threadIdx.x;  // float4 index
        const float* src;
        __hip_bfloat16* dst;
        int off;
        if (idx < 524288) { dst = xin; off = idx; src = inputs + (size_t)off * 4; }
        else if (idx < 2621440) { off = idx - 524288; dst = hb; src = h_tm1 + (size_t)off * 4; }
        else {
            const int i = idx - 2621440;
            const int b = i >> 8, c4 = i & 255;
            off = i; dst = ph0;
            src = prev_h + (size_t)b * (UU * SKIPN) + c4 * 4;
        }
        const float4 v = *(const float4*)src;
        union { __hip_bfloat16 h[4]; ushort4_t u; } cv;
        cv.h[0] = __float2bfloat16(v.x);
        cv.h[1] = __float2bfloat16(v.y);
        cv.h[2] = __float2bfloat16(v.z);
        cv.h[3] = __float2bfloat16(v.w);
        *(ushort4_t*)(dst + (size_t)off * 4) = cv.u;
    }
}

// ---------------- mega2: round-2 GEMM blocks interleaved with copy blocks -------
// do_copy=1: grid 768; bid%6==5 -> copy block (cb=bid/6), else gemm gi=(bid/6)*5+bid%6
// do_copy=0: grid 640; all gemm, gi=bid  (scratch may alias out_prev -> no copy)
__global__ __launch_bounds__(256) void mega2(
    const __hip_bfloat16* __restrict__ xin,  // [2048][1024]
    const __hip_bfloat16* __restrict__ hb,   // [2048][4096]
    const __hip_bfloat16* __restrict__ ph0,  // [2048][1024]
    const __hip_bfloat16* __restrict__ kt,   // [4096][1024]
    const __hip_bfloat16* __restrict__ rkt,  // [4096][1024]
    const __hip_bfloat16* __restrict__ k2t,  // [1024][1024]
    const float* __restrict__ prev_h, float* __restrict__ out_prev,
    float* __restrict__ pre,                 // [5][2048][1024] f32
    int do_copy) {
    const int bid = blockIdx.x;
    int gi;
    if (do_copy) {
        const int q = bid / 6, r = bid - q * 6;
        if (r == 5) {
            // ---- copy role: shift prev_h[:, 1024:] -> out_prev[:, :23552) ----
            for (int rr = 0; rr < 16; ++rr) {
                const int b = q * 16 + rr;
                const float4* s = (const float4*)(prev_h + (size_t)b * 24576 + 1024);
                float4* d = (float4*)(out_prev + (size_t)b * 24576);
                for (int c = threadIdx.x; c < 5888; c += 256) d[c] = s[c];
            }
            return;
        }
        gi = q * 5 + r;
    } else {
        gi = bid;
    }
    const int g = gi % 5;            // gate (0..3) or skip (4)
    const int t = gi / 5;            // tile 0..127
    const int v0 = (t & 7) * 128;    // unit-col tile
    const int b0 = (t >> 3) * 128;   // batch-row tile

    __shared__ short As[128 * 32];
    __shared__ short Bs[128 * 32];

    const int tid = threadIdx.x;
    const int lane = tid & 63;
    const int wid = tid >> 6;        // 0..3
    const int wrow = wid >> 1;       // 0..1
    const int wcol = wid & 1;        // 0..1

    const int srow = tid >> 2;                      // 0..63
    const int sslot = tid & 3;
    const int kofs = ((sslot ^ (srow & 3)) << 3);   // swizzled k offset (elems)
    char* dA = (char*)As + wid * 1024;              // wave-uniform LDS dest
    char* dB = (char*)Bs + wid * 1024;

    const int l15 = lane & 15;
    const int hi = lane >> 4;                       // 0..3
    const int rswB = ((hi ^ (l15 & 3)) << 4);       // swizzled read offset (bytes)

    f32x4 acc[4][4];
#pragma unroll
    for (int m = 0; m < 4; m++)
#pragma unroll
        for (int n = 0; n < 4; n++) acc[m][n] = (f32x4){0.f, 0.f, 0.f, 0.f};

    const __hip_bfloat16* A1;
    const __hip_bfloat16* W1;
    const __hip_bfloat16* A2 = nullptr;
    const __hip_bfloat16* W2 = nullptr;
    int lda1;
    if (g < 4) {
        A1 = xin; lda1 = 1024;
        W1 = kt + (size_t)g * 1048576;
        A2 = hb + (size_t)g * 1024;         // ld 4096
        W2 = rkt + (size_t)g * 1048576;
    } else {
        A1 = ph0; lda1 = 1024;
        W1 = k2t;
    }

#define KSEG(AB, LDA, WB)                                                          \
    {                                                                              \
        const __hip_bfloat16* Ar0 = (AB) + (size_t)(b0 + srow) * (LDA) + kofs;     \
        const __hip_bfloat16* Ar1 = (AB) + (size_t)(b0 + 64 + srow) * (LDA) + kofs;\
        const __hip_bfloat16* Wr0 = (WB) + (size_t)(v0 + srow) * 1024 + kofs;      \
        const __hip_bfloat16* Wr1 = (WB) + (size_t)(v0 + 64 + srow) * 1024 + kofs; \
        for (int k0 = 0; k0 < 1024; k0 += 32) {                                    \
            load_lds16(Ar0 + k0, dA);                                              \
            load_lds16(Ar1 + k0, dA + 4096);                                       \
            load_lds16(Wr0 + k0, dB);                                              \
            load_lds16(Wr1 + k0, dB + 4096);                                       \
            __syncthreads();                                                       \
            short8 af[4], bfr[4];                                                  \
            _Pragma("unroll")                                                      \
            for (int m = 0; m < 4; m++)                                            \
                af[m] = *(const short8*)((char*)As + (wrow * 64 + m * 16 + l15) * 64 + rswB); \
            _Pragma("unroll")                                                      \
            for (int n = 0; n < 4; n++)                                            \
                bfr[n] = *(const short8*)((char*)Bs + (wcol * 64 + n * 16 + l15) * 64 + rswB); \
            _Pragma("unroll")                                                      \
            for (int m = 0; m < 4; m++)                                            \
                _Pragma("unroll")                                                  \
                for (int n = 0; n < 4; n++)                                        \
                    acc[m][n] = __builtin_amdgcn_mfma_f32_16x16x32_bf16(af[m], bfr[n], acc[m][n], 0, 0, 0); \
            __syncthreads();                                                       \
        }                                                                          \
    }

    KSEG(A1, lda1, W1);
    if (g < 4) KSEG(A2, 4096, W2);
#undef KSEG

    float* P = pre + (size_t)g * 2097152;
#pragma unroll
    for (int m = 0; m < 4; m++) {
#pragma unroll
        for (int n = 0; n < 4; n++) {
            const int col = v0 + wcol * 64 + n * 16 + l15;
            const int row = b0 + wrow * 64 + m * 16 + hi * 4;
#pragma unroll
            for (int r = 0; r < 4; r++)
                P[(size_t)(row + r) * 1024 + col] = acc[m][n][r];
        }
    }
}

// ---------------- elementwise LSTM epilogue (+ prev tail + step) ----------------
__global__ __launch_bounds__(256) void epilogue2(
    const float* __restrict__ pre,   // [5][2048][1024]
    const float* __restrict__ c_tm1, const float* __restrict__ bias,
    const float* __restrict__ bias2, const float* __restrict__ s0p,
    const float* __restrict__ step, float* __restrict__ out_h,
    float* __restrict__ out_ht, float* __restrict__ out_c,
    float* __restrict__ out_step, float* __restrict__ out_prev, int write_tail) {
    const int idx = blockIdx.x * 256 + threadIdx.x;  // (b, v4)
    const int b = idx >> 8;
    const int v = (idx & 255) * 4;
    const size_t bv = (size_t)b * 1024 + v;
    const float4 pi = *(const float4*)(pre + bv);
    const float4 pf = *(const float4*)(pre + 2097152 + bv);
    const float4 pc = *(const float4*)(pre + 4194304 + bv);
    const float4 po = *(const float4*)(pre + 6291456 + bv);
    const float4 ps = *(const float4*)(pre + 8388608 + bv);
    const float4 ct = *(const float4*)(c_tm1 + bv);
    const float4 bi = *(const float4*)(bias + v);
    const float4 bf_ = *(const float4*)(bias + 1024 + v);
    const float4 bc = *(const float4*)(bias + 2048 + v);
    const float4 bo = *(const float4*)(bias + 3072 + v);
    const float4 b2 = *(const float4*)(bias2 + v);
    const float s0 = s0p[0];

    float4 hv, iv4, fv4, cn4, ov4;
#pragma unroll
    for (int j = 0; j < 4; j++) {
        const float iv = sigmoidf_(((const float*)&pi)[j] + ((const float*)&bi)[j]);
        const float fv = sigmoidf_(((const float*)&pf)[j] + ((const float*)&bf_)[j]);
        const float cn = fv * ((const float*)&ct)[j] + iv * tanhf(((const float*)&pc)[j] + ((const float*)&bc)[j]);
        const float ov = sigmoidf_(((const float*)&po)[j] + ((const float*)&bo)[j]);
        const float sk = sigmoidf_(((const float*)&ps)[j] + ((const float*)&b2)[j]);
        ((float*)&hv)[j] = s0 * (ov * tanhf(cn)) + sk * (1.0f - s0);
        ((float*)&iv4)[j] = iv;
        ((float*)&fv4)[j] = fv;
        ((float*)&cn4)[j] = cn;
        ((float*)&ov4)[j] = ov;
    }
    *(float4*)(out_h + bv) = hv;
    *(float4*)(out_c + bv) = cn4;
    float* ht = out_ht + (size_t)b * 4096 + v;
    *(float4*)(ht) = iv4;
    *(float4*)(ht + 1024) = fv4;
    *(float4*)(ht + 2048) = cn4;
    *(float4*)(ht + 3072) = ov4;
    if (write_tail)
        *(float4*)(out_prev + (size_t)b * 24576 + 23552 + v) = hv;
    if (idx < 2048) out_step[idx] = step[idx] + 1.0f;
}

// ---------------- fallback shift (scratch aliased in out_prev) -------------------
__global__ __launch_bounds__(512) void shift_only(
    const float* __restrict__ prev_h, const float* __restrict__ out_h,
    float* __restrict__ out_prev) {
    const int cb = blockIdx.x;  // 0..127
    for (int r = 0; r < 16; ++r) {
        const int b = cb * 16 + r;
        float4* d = (float4*)(out_prev + (size_t)b * 24576);
        const float4* s1 = (const float4*)(prev_h + (size_t)b * 24576 + 1024);
        const float4* s2 = (const float4*)(out_h + (size_t)b * 1024);
        for (int c = threadIdx.x; c < 6144; c += 512)
            d[c] = (c < 5888) ? s1[c] : s2[c - 5888];
    }
}

extern "C" void kernel_launch(void* const* d_in, const int* in_sizes, int n_in,
                              void* d_out, int out_size, void* d_ws, size_t ws_size,
                              hipStream_t stream) {
    (void)in_sizes; (void)n_in; (void)out_size;
    const float* inputs = (const float*)d_in[0];
    const float* h_tm1 = (const float*)d_in[1];
    const float* c_tm1 = (const float*)d_in[2];
    const float* step = (const float*)d_in[3];
    const float* prev_h = (const float*)d_in[4];
    const float* kernel = (const float*)d_in[5];
    const float* rkernel = (const float*)d_in[6];
    const float* kernel2 = (const float*)d_in[7];
    const float* bias = (const float*)d_in[8];
    const float* bias2 = (const float*)d_in[9];
    const float* s0 = (const float*)d_in[10];

    float* out = (float*)d_out;
    float* out_h = out;                // [B,U]
    float* out_ht = out + 2097152;     // [B,4U]
    float* out_c = out + 10485760;     // [B,U]
    float* out_step = out + 12582912;  // [B,1]
    float* out_prev = out + 12584960;  // [B,U*SKIP]

    const size_t NEED = 44040192 + 41943040;  // 42MB bf16 scratch + 40MB fp32 pre
    const int fits = (ws_size >= NEED);
    char* scr = fits ? (char*)d_ws : (char*)out_prev;
    __hip_bfloat16* kt = (__hip_bfloat16*)(scr + 0);           // [4096][1024]
    __hip_bfloat16* rkt = (__hip_bfloat16*)(scr + 8388608);    // [4096][1024]
    __hip_bfloat16* k2t = (__hip_bfloat16*)(scr + 16777216);   // [1024][1024]
    __hip_bfloat16* xin = (__hip_bfloat16*)(scr + 18874368);   // [2048][1024]
    __hip_bfloat16* hb = (__hip_bfloat16*)(scr + 23068672);    // [2048][4096]
    __hip_bfloat16* ph0 = (__hip_bfloat16*)(scr + 39845888);   // [2048][1024]
    float* pre = (float*)(scr + 44040192);                     // [5][2048][1024]

    prep<<<21504, 256, 0, stream>>>(inputs, h_tm1, prev_h, kernel, rkernel, kernel2,
                                    kt, rkt, k2t, xin, hb, ph0);
    if (fits) {
        mega2<<<768, 256, 0, stream>>>(xin, hb, ph0, kt, rkt, k2t, prev_h, out_prev, pre, 1);
        epilogue2<<<2048, 256, 0, stream>>>(pre, c_tm1, bias, bias2, s0, step,
                                            out_h, out_ht, out_c, out_step, out_prev, 1);
    } else {
        mega2<<<640, 256, 0, stream>>>(xin, hb, ph0, kt, rkt, k2t, prev_h, out_prev, pre, 0);
        epilogue2<<<2048, 256, 0, stream>>>(pre, c_tm1, bias, bias2, s0, step,
                                            out_h, out_ht, out_c, out_step, out_prev, 0);
        shift_only<<<128, 512, 0, stream>>>(prev_h, out_h, out_prev);
    }
}

// Round 5
// 196.757 us; speedup vs baseline: 1.7060x; 1.7060x over previous
//
#include <hip/hip_runtime.h>
#include <hip/hip_bf16.h>
#include <stdint.h>

#define BB 2048
#define UU 1024
#define SKIPN 24

typedef __attribute__((ext_vector_type(8))) short short8;
typedef __attribute__((ext_vector_type(4))) float f32x4;
typedef __attribute__((ext_vector_type(4))) unsigned short ushort4_t;

static __device__ __forceinline__ float sigmoidf_(float x) {
    return 1.0f / (1.0f + __expf(-x));
}

static __device__ __forceinline__ void load_lds16(const void* g, void* l) {
    __builtin_amdgcn_global_load_lds((const __attribute__((address_space(1))) void*)g,
                                     (__attribute__((address_space(3))) void*)l, 16, 0, 0);
}

// ---------------- prep: weight transpose->bf16 + activation convert->bf16 -------
__global__ __launch_bounds__(256) void prep(
    const float* __restrict__ inputs, const float* __restrict__ h_tm1,
    const float* __restrict__ prev_h, const float* __restrict__ kernel,
    const float* __restrict__ rkernel, const float* __restrict__ kernel2,
    __hip_bfloat16* __restrict__ kt, __hip_bfloat16* __restrict__ rkt,
    __hip_bfloat16* __restrict__ k2t, __hip_bfloat16* __restrict__ xin,
    __hip_bfloat16* __restrict__ hb, __hip_bfloat16* __restrict__ ph0) {
    const int bid = blockIdx.x;
    if (bid < 9216) {
        __shared__ float tile[32][33];
        const float* src;
        __hip_bfloat16* dst;
        int C, local;
        if (bid < 4096)      { src = kernel;  dst = kt;  C = 4096; local = bid; }
        else if (bid < 8192) { src = rkernel; dst = rkt; C = 4096; local = bid - 4096; }
        else                 { src = kernel2; dst = k2t; C = 1024; local = bid - 8192; }
        const int xt = (C == 4096) ? 128 : 32;
        const int bc = (local % xt) * 32;
        const int br = (local / xt) * 32;
        const int tx = threadIdx.x & 31, ty = threadIdx.x >> 5;
#pragma unroll
        for (int i = 0; i < 32; i += 8)
            tile[ty + i][tx] = src[(size_t)(br + ty + i) * C + bc + tx];
        __syncthreads();
#pragma unroll
        for (int i = 0; i < 32; i += 8)
            dst[(size_t)(bc + ty + i) * 1024 + br + tx] = __float2bfloat16(tile[tx][ty + i]);
    } else {
        const int idx = (bid - 9216) * 256 + threadIdx.x;  // float4 index
        const float* src;
        __hip_bfloat16* dst;
        int off;
        if (idx < 524288) { dst = xin; off = idx; src = inputs + (size_t)off * 4; }
        else if (idx < 2621440) { off = idx - 524288; dst = hb; src = h_tm1 + (size_t)off * 4; }
        else {
            const int i = idx - 2621440;
            const int b = i >> 8, c4 = i & 255;
            off = i; dst = ph0;
            src = prev_h + (size_t)b * (UU * SKIPN) + c4 * 4;
        }
        const float4 v = *(const float4*)src;
        union { __hip_bfloat16 h[4]; ushort4_t u; } cv;
        cv.h[0] = __float2bfloat16(v.x);
        cv.h[1] = __float2bfloat16(v.y);
        cv.h[2] = __float2bfloat16(v.z);
        cv.h[3] = __float2bfloat16(v.w);
        *(ushort4_t*)(dst + (size_t)off * 4) = cv.u;
    }
}

// ---------------- mega3: GEMM blocks [0,640) + copy blocks [640,2688) -----------
// do_copy=0: grid 640, all gemm (scratch aliases out_prev -> no copy role)
__global__ __launch_bounds__(256) void mega3(
    const __hip_bfloat16* __restrict__ xin,  // [2048][1024]
    const __hip_bfloat16* __restrict__ hb,   // [2048][4096]
    const __hip_bfloat16* __restrict__ ph0,  // [2048][1024]
    const __hip_bfloat16* __restrict__ kt,   // [4096][1024]
    const __hip_bfloat16* __restrict__ rkt,  // [4096][1024]
    const __hip_bfloat16* __restrict__ k2t,  // [1024][1024]
    const float* __restrict__ prev_h, float* __restrict__ out_prev,
    float* __restrict__ pre) {               // [5][2048][1024] f32
    const int bid = blockIdx.x;
    if (bid >= 640) {
        // ---- copy role: one batch-row per block, 8 blocks/CU co-resident ----
        const int b = bid - 640;  // 0..2047
        const float4* s = (const float4*)(prev_h + (size_t)b * 24576 + 1024);
        float4* d = (float4*)(out_prev + (size_t)b * 24576);
        for (int c = threadIdx.x; c < 5888; c += 256) d[c] = s[c];
        return;
    }
    const int gi = bid;
    const int g = gi % 5;            // gate (0..3) or skip (4)
    const int t = gi / 5;            // tile 0..127
    const int v0 = (t & 7) * 128;    // unit-col tile
    const int b0 = (t >> 3) * 128;   // batch-row tile

    __shared__ short As[128 * 32];
    __shared__ short Bs[128 * 32];

    const int tid = threadIdx.x;
    const int lane = tid & 63;
    const int wid = tid >> 6;        // 0..3
    const int wrow = wid >> 1;       // 0..1
    const int wcol = wid & 1;        // 0..1

    const int srow = tid >> 2;                      // 0..63
    const int sslot = tid & 3;
    const int kofs = ((sslot ^ (srow & 3)) << 3);   // swizzled k offset (elems)
    char* dA = (char*)As + wid * 1024;              // wave-uniform LDS dest
    char* dB = (char*)Bs + wid * 1024;

    const int l15 = lane & 15;
    const int hi = lane >> 4;                       // 0..3
    const int rswB = ((hi ^ (l15 & 3)) << 4);       // swizzled read offset (bytes)

    f32x4 acc[4][4];
#pragma unroll
    for (int m = 0; m < 4; m++)
#pragma unroll
        for (int n = 0; n < 4; n++) acc[m][n] = (f32x4){0.f, 0.f, 0.f, 0.f};

    const __hip_bfloat16* A1;
    const __hip_bfloat16* W1;
    const __hip_bfloat16* A2 = nullptr;
    const __hip_bfloat16* W2 = nullptr;
    int lda1;
    if (g < 4) {
        A1 = xin; lda1 = 1024;
        W1 = kt + (size_t)g * 1048576;
        A2 = hb + (size_t)g * 1024;         // ld 4096
        W2 = rkt + (size_t)g * 1048576;
    } else {
        A1 = ph0; lda1 = 1024;
        W1 = k2t;
    }

#define KSEG(AB, LDA, WB)                                                          \
    {                                                                              \
        const __hip_bfloat16* Ar0 = (AB) + (size_t)(b0 + srow) * (LDA) + kofs;     \
        const __hip_bfloat16* Ar1 = (AB) + (size_t)(b0 + 64 + srow) * (LDA) + kofs;\
        const __hip_bfloat16* Wr0 = (WB) + (size_t)(v0 + srow) * 1024 + kofs;      \
        const __hip_bfloat16* Wr1 = (WB) + (size_t)(v0 + 64 + srow) * 1024 + kofs; \
        for (int k0 = 0; k0 < 1024; k0 += 32) {                                    \
            load_lds16(Ar0 + k0, dA);                                              \
            load_lds16(Ar1 + k0, dA + 4096);                                       \
            load_lds16(Wr0 + k0, dB);                                              \
            load_lds16(Wr1 + k0, dB + 4096);                                       \
            __syncthreads();                                                       \
            short8 af[4], bfr[4];                                                  \
            _Pragma("unroll")                                                      \
            for (int m = 0; m < 4; m++)                                            \
                af[m] = *(const short8*)((char*)As + (wrow * 64 + m * 16 + l15) * 64 + rswB); \
            _Pragma("unroll")                                                      \
            for (int n = 0; n < 4; n++)                                            \
                bfr[n] = *(const short8*)((char*)Bs + (wcol * 64 + n * 16 + l15) * 64 + rswB); \
            _Pragma("unroll")                                                      \
            for (int m = 0; m < 4; m++)                                            \
                _Pragma("unroll")                                                  \
                for (int n = 0; n < 4; n++)                                        \
                    acc[m][n] = __builtin_amdgcn_mfma_f32_16x16x32_bf16(af[m], bfr[n], acc[m][n], 0, 0, 0); \
            __syncthreads();                                                       \
        }                                                                          \
    }

    KSEG(A1, lda1, W1);
    if (g < 4) KSEG(A2, 4096, W2);
#undef KSEG

    float* P = pre + (size_t)g * 2097152;
#pragma unroll
    for (int m = 0; m < 4; m++) {
#pragma unroll
        for (int n = 0; n < 4; n++) {
            const int col = v0 + wcol * 64 + n * 16 + l15;
            const int row = b0 + wrow * 64 + m * 16 + hi * 4;
#pragma unroll
            for (int r = 0; r < 4; r++)
                P[(size_t)(row + r) * 1024 + col] = acc[m][n][r];
        }
    }
}

// ---------------- elementwise LSTM epilogue (+ prev tail + step) ----------------
__global__ __launch_bounds__(256) void epilogue2(
    const float* __restrict__ pre,   // [5][2048][1024]
    const float* __restrict__ c_tm1, const float* __restrict__ bias,
    const float* __restrict__ bias2, const float* __restrict__ s0p,
    const float* __restrict__ step, float* __restrict__ out_h,
    float* __restrict__ out_ht, float* __restrict__ out_c,
    float* __restrict__ out_step, float* __restrict__ out_prev, int write_tail) {
    const int idx = blockIdx.x * 256 + threadIdx.x;  // (b, v4)
    const int b = idx >> 8;
    const int v = (idx & 255) * 4;
    const size_t bv = (size_t)b * 1024 + v;
    const float4 pi = *(const float4*)(pre + bv);
    const float4 pf = *(const float4*)(pre + 2097152 + bv);
    const float4 pc = *(const float4*)(pre + 4194304 + bv);
    const float4 po = *(const float4*)(pre + 6291456 + bv);
    const float4 ps = *(const float4*)(pre + 8388608 + bv);
    const float4 ct = *(const float4*)(c_tm1 + bv);
    const float4 bi = *(const float4*)(bias + v);
    const float4 bf_ = *(const float4*)(bias + 1024 + v);
    const float4 bc = *(const float4*)(bias + 2048 + v);
    const float4 bo = *(const float4*)(bias + 3072 + v);
    const float4 b2 = *(const float4*)(bias2 + v);
    const float s0 = s0p[0];

    float4 hv, iv4, fv4, cn4, ov4;
#pragma unroll
    for (int j = 0; j < 4; j++) {
        const float iv = sigmoidf_(((const float*)&pi)[j] + ((const float*)&bi)[j]);
        const float fv = sigmoidf_(((const float*)&pf)[j] + ((const float*)&bf_)[j]);
        const float cn = fv * ((const float*)&ct)[j] + iv * tanhf(((const float*)&pc)[j] + ((const float*)&bc)[j]);
        const float ov = sigmoidf_(((const float*)&po)[j] + ((const float*)&bo)[j]);
        const float sk = sigmoidf_(((const float*)&ps)[j] + ((const float*)&b2)[j]);
        ((float*)&hv)[j] = s0 * (ov * tanhf(cn)) + sk * (1.0f - s0);
        ((float*)&iv4)[j] = iv;
        ((float*)&fv4)[j] = fv;
        ((float*)&cn4)[j] = cn;
        ((float*)&ov4)[j] = ov;
    }
    *(float4*)(out_h + bv) = hv;
    *(float4*)(out_c + bv) = cn4;
    float* ht = out_ht + (size_t)b * 4096 + v;
    *(float4*)(ht) = iv4;
    *(float4*)(ht + 1024) = fv4;
    *(float4*)(ht + 2048) = cn4;
    *(float4*)(ht + 3072) = ov4;
    if (write_tail)
        *(float4*)(out_prev + (size_t)b * 24576 + 23552 + v) = hv;
    if (idx < 2048) out_step[idx] = step[idx] + 1.0f;
}

// ---------------- fallback shift (scratch aliased in out_prev) -------------------
__global__ __launch_bounds__(256) void shift_only(
    const float* __restrict__ prev_h, const float* __restrict__ out_h,
    float* __restrict__ out_prev) {
    const int b = blockIdx.x;  // 0..2047
    float4* d = (float4*)(out_prev + (size_t)b * 24576);
    const float4* s1 = (const float4*)(prev_h + (size_t)b * 24576 + 1024);
    const float4* s2 = (const float4*)(out_h + (size_t)b * 1024);
    for (int c = threadIdx.x; c < 6144; c += 256)
        d[c] = (c < 5888) ? s1[c] : s2[c - 5888];
}

extern "C" void kernel_launch(void* const* d_in, const int* in_sizes, int n_in,
                              void* d_out, int out_size, void* d_ws, size_t ws_size,
                              hipStream_t stream) {
    (void)in_sizes; (void)n_in; (void)out_size;
    const float* inputs = (const float*)d_in[0];
    const float* h_tm1 = (const float*)d_in[1];
    const float* c_tm1 = (const float*)d_in[2];
    const float* step = (const float*)d_in[3];
    const float* prev_h = (const float*)d_in[4];
    const float* kernel = (const float*)d_in[5];
    const float* rkernel = (const float*)d_in[6];
    const float* kernel2 = (const float*)d_in[7];
    const float* bias = (const float*)d_in[8];
    const float* bias2 = (const float*)d_in[9];
    const float* s0 = (const float*)d_in[10];

    float* out = (float*)d_out;
    float* out_h = out;                // [B,U]
    float* out_ht = out + 2097152;     // [B,4U]
    float* out_c = out + 10485760;     // [B,U]
    float* out_step = out + 12582912;  // [B,1]
    float* out_prev = out + 12584960;  // [B,U*SKIP]

    const size_t NEED = 44040192 + 41943040;  // 42MB bf16 scratch + 40MB fp32 pre
    const int fits = (ws_size >= NEED);
    char* scr = fits ? (char*)d_ws : (char*)out_prev;
    __hip_bfloat16* kt = (__hip_bfloat16*)(scr + 0);           // [4096][1024]
    __hip_bfloat16* rkt = (__hip_bfloat16*)(scr + 8388608);    // [4096][1024]
    __hip_bfloat16* k2t = (__hip_bfloat16*)(scr + 16777216);   // [1024][1024]
    __hip_bfloat16* xin = (__hip_bfloat16*)(scr + 18874368);   // [2048][1024]
    __hip_bfloat16* hb = (__hip_bfloat16*)(scr + 23068672);    // [2048][4096]
    __hip_bfloat16* ph0 = (__hip_bfloat16*)(scr + 39845888);   // [2048][1024]
    float* pre = (float*)(scr + 44040192);                     // [5][2048][1024]

    prep<<<21504, 256, 0, stream>>>(inputs, h_tm1, prev_h, kernel, rkernel, kernel2,
                                    kt, rkt, k2t, xin, hb, ph0);
    if (fits) {
        mega3<<<2688, 256, 0, stream>>>(xin, hb, ph0, kt, rkt, k2t, prev_h, out_prev, pre);
        epilogue2<<<2048, 256, 0, stream>>>(pre, c_tm1, bias, bias2, s0, step,
                                            out_h, out_ht, out_c, out_step, out_prev, 1);
    } else {
        mega3<<<640, 256, 0, stream>>>(xin, hb, ph0, kt, rkt, k2t, prev_h, out_prev, pre);
        epilogue2<<<2048, 256, 0, stream>>>(pre, c_tm1, bias, bias2, s0, step,
                                            out_h, out_ht, out_c, out_step, out_prev, 0);
        shift_only<<<2048, 256, 0, stream>>>(prev_h, out_h, out_prev);
    }
}

// Round 7
// 173.834 us; speedup vs baseline: 1.9310x; 1.1319x over previous
//
#include <hip/hip_runtime.h>
#include <hip/hip_bf16.h>
#include <stdint.h>

#define BB 2048
#define UU 1024
#define SKIPN 24

typedef __attribute__((ext_vector_type(8))) short short8;
typedef __attribute__((ext_vector_type(4))) float f32x4;
typedef __attribute__((ext_vector_type(4))) unsigned short ushort4_t;

static __device__ __forceinline__ float sigmoidf_(float x) {
    return 1.0f / (1.0f + __expf(-x));
}

static __device__ __forceinline__ void load_lds16(const void* g, void* l) {
    __builtin_amdgcn_global_load_lds((const __attribute__((address_space(1))) void*)g,
                                     (__attribute__((address_space(3))) void*)l, 16, 0, 0);
}

static __device__ __forceinline__ f32x4 ntl(const f32x4* p) {
    return __builtin_nontemporal_load(p);
}
static __device__ __forceinline__ void nts(f32x4* p, f32x4 v) {
    __builtin_nontemporal_store(v, p);
}

// ---------------- prep: weight transpose->bf16 + activation convert->bf16 -------
__global__ __launch_bounds__(256) void prep(
    const float* __restrict__ inputs, const float* __restrict__ h_tm1,
    const float* __restrict__ prev_h, const float* __restrict__ kernel,
    const float* __restrict__ rkernel, const float* __restrict__ kernel2,
    __hip_bfloat16* __restrict__ kt, __hip_bfloat16* __restrict__ rkt,
    __hip_bfloat16* __restrict__ k2t, __hip_bfloat16* __restrict__ xin,
    __hip_bfloat16* __restrict__ hb, __hip_bfloat16* __restrict__ ph0) {
    const int bid = blockIdx.x;
    if (bid < 9216) {
        __shared__ float tile[32][33];
        const float* src;
        __hip_bfloat16* dst;
        int C, local;
        if (bid < 4096)      { src = kernel;  dst = kt;  C = 4096; local = bid; }
        else if (bid < 8192) { src = rkernel; dst = rkt; C = 4096; local = bid - 4096; }
        else                 { src = kernel2; dst = k2t; C = 1024; local = bid - 8192; }
        const int xt = (C == 4096) ? 128 : 32;
        const int bc = (local % xt) * 32;
        const int br = (local / xt) * 32;
        const int tx = threadIdx.x & 31, ty = threadIdx.x >> 5;
#pragma unroll
        for (int i = 0; i < 32; i += 8)
            tile[ty + i][tx] = src[(size_t)(br + ty + i) * C + bc + tx];
        __syncthreads();
#pragma unroll
        for (int i = 0; i < 32; i += 8)
            dst[(size_t)(bc + ty + i) * 1024 + br + tx] = __float2bfloat16(tile[tx][ty + i]);
    } else {
        const int idx = (bid - 9216) * 256 + threadIdx.x;  // float4 index
        const float* src;
        __hip_bfloat16* dst;
        int off;
        if (idx < 524288) { dst = xin; off = idx; src = inputs + (size_t)off * 4; }
        else if (idx < 2621440) { off = idx - 524288; dst = hb; src = h_tm1 + (size_t)off * 4; }
        else {
            const int i = idx - 2621440;
            const int b = i >> 8, c4 = i & 255;
            off = i; dst = ph0;
            src = prev_h + (size_t)b * (UU * SKIPN) + c4 * 4;
        }
        const float4 v = *(const float4*)src;
        union { __hip_bfloat16 h[4]; ushort4_t u; } cv;
        cv.h[0] = __float2bfloat16(v.x);
        cv.h[1] = __float2bfloat16(v.y);
        cv.h[2] = __float2bfloat16(v.z);
        cv.h[3] = __float2bfloat16(v.w);
        *(ushort4_t*)(dst + (size_t)off * 4) = cv.u;
    }
}

// ---------------- mega4: dbuf GEMM blocks [0,640) + nt-copy blocks [640,2688) ---
__global__ __launch_bounds__(256) void mega4(
    const __hip_bfloat16* __restrict__ xin,  // [2048][1024]
    const __hip_bfloat16* __restrict__ hb,   // [2048][4096]
    const __hip_bfloat16* __restrict__ ph0,  // [2048][1024]
    const __hip_bfloat16* __restrict__ kt,   // [4096][1024]
    const __hip_bfloat16* __restrict__ rkt,  // [4096][1024]
    const __hip_bfloat16* __restrict__ k2t,  // [1024][1024]
    const float* __restrict__ prev_h, float* __restrict__ out_prev,
    float* __restrict__ pre) {               // [5][2048][1024] f32
    const int bid = blockIdx.x;
    if (bid >= 640) {
        // ---- copy role: one batch-row per block, non-temporal, 4-deep MLP ----
        const int b = bid - 640;  // 0..2047
        const f32x4* s = (const f32x4*)(prev_h + (size_t)b * 24576 + 1024);
        f32x4* d = (f32x4*)(out_prev + (size_t)b * 24576);
        int c = threadIdx.x;
#pragma unroll 1
        for (int it = 0; it < 5; ++it) {  // 20 of 23 float4 per thread
            f32x4 v0 = ntl(s + c);
            f32x4 v1 = ntl(s + c + 256);
            f32x4 v2 = ntl(s + c + 512);
            f32x4 v3 = ntl(s + c + 768);
            nts(d + c, v0);
            nts(d + c + 256, v1);
            nts(d + c + 512, v2);
            nts(d + c + 768, v3);
            c += 1024;
        }
        {   // tail 3 (c = tid + 5120; 5888 - 5120 = 768)
            f32x4 v0 = ntl(s + c);
            f32x4 v1 = ntl(s + c + 256);
            f32x4 v2 = ntl(s + c + 512);
            nts(d + c, v0);
            nts(d + c + 256, v1);
            nts(d + c + 512, v2);
        }
        return;
    }
    const int gi = bid;
    const int g = gi % 5;            // gate (0..3) or skip (4)
    const int t = gi / 5;            // tile 0..127
    const int v0 = (t & 7) * 128;    // unit-col tile
    const int b0 = (t >> 3) * 128;   // batch-row tile

    __shared__ char As[2 * 8192];    // [buf][128 rows][32 bf16]
    __shared__ char Bs[2 * 8192];

    const int tid = threadIdx.x;
    const int lane = tid & 63;
    const int wid = tid >> 6;        // 0..3
    const int wrow = wid >> 1;       // 0..1
    const int wcol = wid & 1;        // 0..1

    const int srow = tid >> 2;                      // 0..63
    const int sslot = tid & 3;
    const int kofs = ((sslot ^ (srow & 3)) << 3);   // swizzled k offset (elems)
    const int ldst = wid * 1024;                    // wave-uniform LDS dest offset

    const int l15 = lane & 15;
    const int hi = lane >> 4;                       // 0..3
    const int rswB = ((hi ^ (l15 & 3)) << 4);       // swizzled read offset (bytes)

    f32x4 acc[4][4];
#pragma unroll
    for (int m = 0; m < 4; m++)
#pragma unroll
        for (int n = 0; n < 4; n++) acc[m][n] = (f32x4){0.f, 0.f, 0.f, 0.f};

    const __hip_bfloat16* A1;
    const __hip_bfloat16* W1;
    const __hip_bfloat16* A2 = nullptr;
    const __hip_bfloat16* W2 = nullptr;
    int lda1;
    if (g < 4) {
        A1 = xin; lda1 = 1024;
        W1 = kt + (size_t)g * 1048576;
        A2 = hb + (size_t)g * 1024;         // ld 4096
        W2 = rkt + (size_t)g * 1048576;
    } else {
        A1 = ph0; lda1 = 1024;
        W1 = k2t;
    }

#define BARRIER() asm volatile("s_barrier" ::: "memory")
#define WAITV(N) asm volatile("s_waitcnt vmcnt(" #N ")" ::: "memory")
#define WAITL0() asm volatile("s_waitcnt lgkmcnt(0)" ::: "memory")

// dbuf K-segment: STAGE(t+1) before compute(t); counted vmcnt(4) drain
#define KSEG(AB, LDA, WB)                                                          \
    {                                                                              \
        const __hip_bfloat16* Ar0 = (AB) + (size_t)(b0 + srow) * (LDA) + kofs;     \
        const __hip_bfloat16* Ar1 = (AB) + (size_t)(b0 + 64 + srow) * (LDA) + kofs;\
        const __hip_bfloat16* Wr0 = (WB) + (size_t)(v0 + srow) * 1024 + kofs;      \
        const __hip_bfloat16* Wr1 = (WB) + (size_t)(v0 + 64 + srow) * 1024 + kofs; \
        load_lds16(Ar0, As + ldst);                                                \
        load_lds16(Ar1, As + ldst + 4096);                                         \
        load_lds16(Wr0, Bs + ldst);                                                \
        load_lds16(Wr1, Bs + ldst + 4096);                                         \
        _Pragma("unroll 2")                                                        \
        for (int t_ = 0; t_ < 32; ++t_) {                                          \
            const int cur = t_ & 1;                                                \
            char* Ac = As + cur * 8192;                                            \
            char* Bc = Bs + cur * 8192;                                            \
            if (t_ < 31) {                                                         \
                const int kn = (t_ + 1) * 32;                                      \
                char* An = As + (cur ^ 1) * 8192 + ldst;                           \
                char* Bn = Bs + (cur ^ 1) * 8192 + ldst;                           \
                load_lds16(Ar0 + kn, An);                                          \
                load_lds16(Ar1 + kn, An + 4096);                                   \
                load_lds16(Wr0 + kn, Bn);                                          \
                load_lds16(Wr1 + kn, Bn + 4096);                                   \
                WAITV(4);                                                          \
            } else {                                                               \
                WAITV(0);                                                          \
            }                                                                      \
            BARRIER();                                                             \
            short8 af[4], bfr[4];                                                  \
            _Pragma("unroll")                                                      \
            for (int m = 0; m < 4; m++)                                            \
                af[m] = *(const short8*)(Ac + (wrow * 64 + m * 16 + l15) * 64 + rswB); \
            _Pragma("unroll")                                                      \
            for (int n = 0; n < 4; n++)                                            \
                bfr[n] = *(const short8*)(Bc + (wcol * 64 + n * 16 + l15) * 64 + rswB); \
            _Pragma("unroll")                                                      \
            for (int m = 0; m < 4; m++)                                            \
                _Pragma("unroll")                                                  \
                for (int n = 0; n < 4; n++)                                        \
                    acc[m][n] = __builtin_amdgcn_mfma_f32_16x16x32_bf16(af[m], bfr[n], acc[m][n], 0, 0, 0); \
            WAITL0();                                                              \
            BARRIER();                                                             \
        }                                                                          \
    }

    KSEG(A1, lda1, W1);
    if (g < 4) KSEG(A2, 4096, W2);
#undef KSEG

    float* P = pre + (size_t)g * 2097152;
#pragma unroll
    for (int m = 0; m < 4; m++) {
#pragma unroll
        for (int n = 0; n < 4; n++) {
            const int col = v0 + wcol * 64 + n * 16 + l15;
            const int row = b0 + wrow * 64 + m * 16 + hi * 4;
#pragma unroll
            for (int r = 0; r < 4; r++)
                P[(size_t)(row + r) * 1024 + col] = acc[m][n][r];
        }
    }
#undef BARRIER
#undef WAITV
#undef WAITL0
}

// ---------------- elementwise LSTM epilogue (+ prev tail + step) ----------------
__global__ __launch_bounds__(256) void epilogue2(
    const float* __restrict__ pre,   // [5][2048][1024]
    const float* __restrict__ c_tm1, const float* __restrict__ bias,
    const float* __restrict__ bias2, const float* __restrict__ s0p,
    const float* __restrict__ step, float* __restrict__ out_h,
    float* __restrict__ out_ht, float* __restrict__ out_c,
    float* __restrict__ out_step, float* __restrict__ out_prev, int write_tail) {
    const int idx = blockIdx.x * 256 + threadIdx.x;  // (b, v4)
    const int b = idx >> 8;
    const int v = (idx & 255) * 4;
    const size_t bv = (size_t)b * 1024 + v;
    const float4 pi = *(const float4*)(pre + bv);
    const float4 pf = *(const float4*)(pre + 2097152 + bv);
    const float4 pc = *(const float4*)(pre + 4194304 + bv);
    const float4 po = *(const float4*)(pre + 6291456 + bv);
    const float4 ps = *(const float4*)(pre + 8388608 + bv);
    const float4 ct = *(const float4*)(c_tm1 + bv);
    const float4 bi = *(const float4*)(bias + v);
    const float4 bf_ = *(const float4*)(bias + 1024 + v);
    const float4 bc = *(const float4*)(bias + 2048 + v);
    const float4 bo = *(const float4*)(bias + 3072 + v);
    const float4 b2 = *(const float4*)(bias2 + v);
    const float s0 = s0p[0];

    float4 hv, iv4, fv4, cn4, ov4;
#pragma unroll
    for (int j = 0; j < 4; j++) {
        const float iv = sigmoidf_(((const float*)&pi)[j] + ((const float*)&bi)[j]);
        const float fv = sigmoidf_(((const float*)&pf)[j] + ((const float*)&bf_)[j]);
        const float cn = fv * ((const float*)&ct)[j] + iv * tanhf(((const float*)&pc)[j] + ((const float*)&bc)[j]);
        const float ov = sigmoidf_(((const float*)&po)[j] + ((const float*)&bo)[j]);
        const float sk = sigmoidf_(((const float*)&ps)[j] + ((const float*)&b2)[j]);
        ((float*)&hv)[j] = s0 * (ov * tanhf(cn)) + sk * (1.0f - s0);
        ((float*)&iv4)[j] = iv;
        ((float*)&fv4)[j] = fv;
        ((float*)&cn4)[j] = cn;
        ((float*)&ov4)[j] = ov;
    }
    *(float4*)(out_h + bv) = hv;
    *(float4*)(out_c + bv) = cn4;
    float* ht = out_ht + (size_t)b * 4096 + v;
    *(float4*)(ht) = iv4;
    *(float4*)(ht + 1024) = fv4;
    *(float4*)(ht + 2048) = cn4;
    *(float4*)(ht + 3072) = ov4;
    if (write_tail)
        *(float4*)(out_prev + (size_t)b * 24576 + 23552 + v) = hv;
    if (idx < 2048) out_step[idx] = step[idx] + 1.0f;
}

// ---------------- fallback shift (scratch aliased in out_prev) -------------------
__global__ __launch_bounds__(256) void shift_only(
    const float* __restrict__ prev_h, const float* __restrict__ out_h,
    float* __restrict__ out_prev) {
    const int b = blockIdx.x;  // 0..2047
    float4* d = (float4*)(out_prev + (size_t)b * 24576);
    const float4* s1 = (const float4*)(prev_h + (size_t)b * 24576 + 1024);
    const float4* s2 = (const float4*)(out_h + (size_t)b * 1024);
    for (int c = threadIdx.x; c < 6144; c += 256)
        d[c] = (c < 5888) ? s1[c] : s2[c - 5888];
}

extern "C" void kernel_launch(void* const* d_in, const int* in_sizes, int n_in,
                              void* d_out, int out_size, void* d_ws, size_t ws_size,
                              hipStream_t stream) {
    (void)in_sizes; (void)n_in; (void)out_size;
    const float* inputs = (const float*)d_in[0];
    const float* h_tm1 = (const float*)d_in[1];
    const float* c_tm1 = (const float*)d_in[2];
    const float* step = (const float*)d_in[3];
    const float* prev_h = (const float*)d_in[4];
    const float* kernel = (const float*)d_in[5];
    const float* rkernel = (const float*)d_in[6];
    const float* kernel2 = (const float*)d_in[7];
    const float* bias = (const float*)d_in[8];
    const float* bias2 = (const float*)d_in[9];
    const float* s0 = (const float*)d_in[10];

    float* out = (float*)d_out;
    float* out_h = out;                // [B,U]
    float* out_ht = out + 2097152;     // [B,4U]
    float* out_c = out + 10485760;     // [B,U]
    float* out_step = out + 12582912;  // [B,1]
    float* out_prev = out + 12584960;  // [B,U*SKIP]

    const size_t NEED = 44040192 + 41943040;  // 42MB bf16 scratch + 40MB fp32 pre
    const int fits = (ws_size >= NEED);
    char* scr = fits ? (char*)d_ws : (char*)out_prev;
    __hip_bfloat16* kt = (__hip_bfloat16*)(scr + 0);           // [4096][1024]
    __hip_bfloat16* rkt = (__hip_bfloat16*)(scr + 8388608);    // [4096][1024]
    __hip_bfloat16* k2t = (__hip_bfloat16*)(scr + 16777216);   // [1024][1024]
    __hip_bfloat16* xin = (__hip_bfloat16*)(scr + 18874368);   // [2048][1024]
    __hip_bfloat16* hb = (__hip_bfloat16*)(scr + 23068672);    // [2048][4096]
    __hip_bfloat16* ph0 = (__hip_bfloat16*)(scr + 39845888);   // [2048][1024]
    float* pre = (float*)(scr + 44040192);                     // [5][2048][1024]

    prep<<<21504, 256, 0, stream>>>(inputs, h_tm1, prev_h, kernel, rkernel, kernel2,
                                    kt, rkt, k2t, xin, hb, ph0);
    if (fits) {
        mega4<<<2688, 256, 0, stream>>>(xin, hb, ph0, kt, rkt, k2t, prev_h, out_prev, pre);
        epilogue2<<<2048, 256, 0, stream>>>(pre, c_tm1, bias, bias2, s0, step,
                                            out_h, out_ht, out_c, out_step, out_prev, 1);
    } else {
        mega4<<<640, 256, 0, stream>>>(xin, hb, ph0, kt, rkt, k2t, prev_h, out_prev, pre);
        epilogue2<<<2048, 256, 0, stream>>>(pre, c_tm1, bias, bias2, s0, step,
                                            out_h, out_ht, out_c, out_step, out_prev, 0);
        shift_only<<<2048, 256, 0, stream>>>(prev_h, out_h, out_prev);
    }
}

// Round 8
// 161.668 us; speedup vs baseline: 2.0763x; 1.0753x over previous
//
#include <hip/hip_runtime.h>
#include <hip/hip_bf16.h>
#include <stdint.h>

#define BB 2048
#define UU 1024
#define SKIPN 24

typedef __attribute__((ext_vector_type(8))) short short8;
typedef __attribute__((ext_vector_type(4))) float f32x4;
typedef __attribute__((ext_vector_type(4))) unsigned short ushort4_t;

static __device__ __forceinline__ float sigmoidf_(float x) {
    return 1.0f / (1.0f + __expf(-x));
}

static __device__ __forceinline__ void load_lds16(const void* g, void* l) {
    __builtin_amdgcn_global_load_lds((const __attribute__((address_space(1))) void*)g,
                                     (__attribute__((address_space(3))) void*)l, 16, 0, 0);
}

static __device__ __forceinline__ f32x4 ntl(const f32x4* p) {
    return __builtin_nontemporal_load(p);
}
static __device__ __forceinline__ void nts(f32x4* p, f32x4 v) {
    __builtin_nontemporal_store(v, p);
}

// ---------------- prep: weight transpose->bf16 + activation convert->bf16 -------
__global__ __launch_bounds__(256) void prep(
    const float* __restrict__ inputs, const float* __restrict__ h_tm1,
    const float* __restrict__ prev_h, const float* __restrict__ kernel,
    const float* __restrict__ rkernel, const float* __restrict__ kernel2,
    __hip_bfloat16* __restrict__ kt, __hip_bfloat16* __restrict__ rkt,
    __hip_bfloat16* __restrict__ k2t, __hip_bfloat16* __restrict__ xin,
    __hip_bfloat16* __restrict__ hb, __hip_bfloat16* __restrict__ ph0) {
    const int bid = blockIdx.x;
    if (bid < 9216) {
        __shared__ float tile[32][33];
        const float* src;
        __hip_bfloat16* dst;
        int C, local;
        if (bid < 4096)      { src = kernel;  dst = kt;  C = 4096; local = bid; }
        else if (bid < 8192) { src = rkernel; dst = rkt; C = 4096; local = bid - 4096; }
        else                 { src = kernel2; dst = k2t; C = 1024; local = bid - 8192; }
        const int xt = (C == 4096) ? 128 : 32;
        const int bc = (local % xt) * 32;
        const int br = (local / xt) * 32;
        const int tx = threadIdx.x & 31, ty = threadIdx.x >> 5;
#pragma unroll
        for (int i = 0; i < 32; i += 8)
            tile[ty + i][tx] = src[(size_t)(br + ty + i) * C + bc + tx];
        __syncthreads();
#pragma unroll
        for (int i = 0; i < 32; i += 8)
            dst[(size_t)(bc + ty + i) * 1024 + br + tx] = __float2bfloat16(tile[tx][ty + i]);
    } else {
        const int idx = (bid - 9216) * 256 + threadIdx.x;  // float4 index
        const float* src;
        __hip_bfloat16* dst;
        int off;
        if (idx < 524288) { dst = xin; off = idx; src = inputs + (size_t)off * 4; }
        else if (idx < 2621440) { off = idx - 524288; dst = hb; src = h_tm1 + (size_t)off * 4; }
        else {
            const int i = idx - 2621440;
            const int b = i >> 8, c4 = i & 255;
            off = i; dst = ph0;
            src = prev_h + (size_t)b * (UU * SKIPN) + c4 * 4;
        }
        const float4 v = *(const float4*)src;
        union { __hip_bfloat16 h[4]; ushort4_t u; } cv;
        cv.h[0] = __float2bfloat16(v.x);
        cv.h[1] = __float2bfloat16(v.y);
        cv.h[2] = __float2bfloat16(v.z);
        cv.h[3] = __float2bfloat16(v.w);
        *(ushort4_t*)(dst + (size_t)off * 4) = cv.u;
    }
}

// ---------------- mega5: 3-buf deep-prefetch GEMM [0,640) + nt-copy [640,2688) --
__global__ __launch_bounds__(256) void mega5(
    const __hip_bfloat16* __restrict__ xin,  // [2048][1024]
    const __hip_bfloat16* __restrict__ hb,   // [2048][4096]
    const __hip_bfloat16* __restrict__ ph0,  // [2048][1024]
    const __hip_bfloat16* __restrict__ kt,   // [4096][1024]
    const __hip_bfloat16* __restrict__ rkt,  // [4096][1024]
    const __hip_bfloat16* __restrict__ k2t,  // [1024][1024]
    const float* __restrict__ prev_h, float* __restrict__ out_prev,
    __hip_bfloat16* __restrict__ pre) {      // [5][2048][1024] bf16
    const int bid = blockIdx.x;
    if (bid >= 640) {
        // ---- copy role: one batch-row per block, non-temporal, 4-deep MLP ----
        const int b = bid - 640;  // 0..2047
        const f32x4* s = (const f32x4*)(prev_h + (size_t)b * 24576 + 1024);
        f32x4* d = (f32x4*)(out_prev + (size_t)b * 24576);
        int c = threadIdx.x;
#pragma unroll 1
        for (int it = 0; it < 5; ++it) {  // 20 of 23 float4 per thread
            f32x4 v0 = ntl(s + c);
            f32x4 v1 = ntl(s + c + 256);
            f32x4 v2 = ntl(s + c + 512);
            f32x4 v3 = ntl(s + c + 768);
            nts(d + c, v0);
            nts(d + c + 256, v1);
            nts(d + c + 512, v2);
            nts(d + c + 768, v3);
            c += 1024;
        }
        {   // tail 3 (c = tid + 5120; 5888 - 5120 = 768)
            f32x4 v0 = ntl(s + c);
            f32x4 v1 = ntl(s + c + 256);
            f32x4 v2 = ntl(s + c + 512);
            nts(d + c, v0);
            nts(d + c + 256, v1);
            nts(d + c + 512, v2);
        }
        return;
    }
    const int gi = bid;
    const int g = gi % 5;            // gate (0..3) or skip (4)
    const int t = gi / 5;            // tile 0..127
    const int v0 = (t & 7) * 128;    // unit-col tile
    const int b0 = (t >> 3) * 128;   // batch-row tile

    __shared__ char As[3 * 8192];    // [buf][128 rows][32 bf16]
    __shared__ char Bs[3 * 8192];

    const int tid = threadIdx.x;
    const int lane = tid & 63;
    const int wid = tid >> 6;        // 0..3
    const int wrow = wid >> 1;       // 0..1
    const int wcol = wid & 1;        // 0..1

    const int srow = tid >> 2;                      // 0..63
    const int sslot = tid & 3;
    const int kofs = ((sslot ^ (srow & 3)) << 3);   // swizzled k offset (elems)
    const int ldst = wid * 1024;                    // wave-uniform LDS dest offset

    const int l15 = lane & 15;
    const int hi = lane >> 4;                       // 0..3
    const int rswB = ((hi ^ (l15 & 3)) << 4);       // swizzled read offset (bytes)

    f32x4 acc[4][4];
#pragma unroll
    for (int m = 0; m < 4; m++)
#pragma unroll
        for (int n = 0; n < 4; n++) acc[m][n] = (f32x4){0.f, 0.f, 0.f, 0.f};

    const __hip_bfloat16* A1;
    const __hip_bfloat16* W1;
    const __hip_bfloat16* A2 = nullptr;
    const __hip_bfloat16* W2 = nullptr;
    int lda1;
    if (g < 4) {
        A1 = xin; lda1 = 1024;
        W1 = kt + (size_t)g * 1048576;
        A2 = hb + (size_t)g * 1024;         // ld 4096
        W2 = rkt + (size_t)g * 1048576;
    } else {
        A1 = ph0; lda1 = 1024;
        W1 = k2t;
    }

#define BARRIER() asm volatile("s_barrier" ::: "memory")
#define WAITV(N) asm volatile("s_waitcnt vmcnt(" #N ")" ::: "memory")
#define WAITL0() asm volatile("s_waitcnt lgkmcnt(0)" ::: "memory")

// 3-buffer K-segment: stage(t+2) each iter; steady-state vmcnt(8)
#define KSEG(AB, LDA, WB)                                                          \
    {                                                                              \
        const __hip_bfloat16* Ar0 = (AB) + (size_t)(b0 + srow) * (LDA) + kofs;     \
        const __hip_bfloat16* Ar1 = (AB) + (size_t)(b0 + 64 + srow) * (LDA) + kofs;\
        const __hip_bfloat16* Wr0 = (WB) + (size_t)(v0 + srow) * 1024 + kofs;      \
        const __hip_bfloat16* Wr1 = (WB) + (size_t)(v0 + 64 + srow) * 1024 + kofs; \
        load_lds16(Ar0, As + ldst);                                                \
        load_lds16(Ar1, As + ldst + 4096);                                         \
        load_lds16(Wr0, Bs + ldst);                                                \
        load_lds16(Wr1, Bs + ldst + 4096);                                         \
        load_lds16(Ar0 + 32, As + 8192 + ldst);                                    \
        load_lds16(Ar1 + 32, As + 8192 + ldst + 4096);                             \
        load_lds16(Wr0 + 32, Bs + 8192 + ldst);                                    \
        load_lds16(Wr1 + 32, Bs + 8192 + ldst + 4096);                             \
        int cur = 0;                                                               \
        for (int t_ = 0; t_ < 32; ++t_) {                                          \
            char* Ac = As + cur * 8192;                                            \
            char* Bc = Bs + cur * 8192;                                            \
            if (t_ < 30) {                                                         \
                int nxt = cur + 2; if (nxt >= 3) nxt -= 3;                         \
                const int kn = (t_ + 2) * 32;                                      \
                char* An = As + nxt * 8192 + ldst;                                 \
                char* Bn = Bs + nxt * 8192 + ldst;                                 \
                load_lds16(Ar0 + kn, An);                                          \
                load_lds16(Ar1 + kn, An + 4096);                                   \
                load_lds16(Wr0 + kn, Bn);                                          \
                load_lds16(Wr1 + kn, Bn + 4096);                                   \
                WAITV(8);                                                          \
            } else if (t_ == 30) {                                                 \
                WAITV(4);                                                          \
            } else {                                                               \
                WAITV(0);                                                          \
            }                                                                      \
            BARRIER();                                                             \
            short8 af[4], bfr[4];                                                  \
            _Pragma("unroll")                                                      \
            for (int m = 0; m < 4; m++)                                            \
                af[m] = *(const short8*)(Ac + (wrow * 64 + m * 16 + l15) * 64 + rswB); \
            _Pragma("unroll")                                                      \
            for (int n = 0; n < 4; n++)                                            \
                bfr[n] = *(const short8*)(Bc + (wcol * 64 + n * 16 + l15) * 64 + rswB); \
            _Pragma("unroll")                                                      \
            for (int m = 0; m < 4; m++)                                            \
                _Pragma("unroll")                                                  \
                for (int n = 0; n < 4; n++)                                        \
                    acc[m][n] = __builtin_amdgcn_mfma_f32_16x16x32_bf16(af[m], bfr[n], acc[m][n], 0, 0, 0); \
            WAITL0();                                                              \
            BARRIER();                                                             \
            cur = (cur == 2) ? 0 : cur + 1;                                        \
        }                                                                          \
    }

    KSEG(A1, lda1, W1);
    if (g < 4) KSEG(A2, 4096, W2);
#undef KSEG

    __hip_bfloat16* P = pre + (size_t)g * 2097152;
#pragma unroll
    for (int m = 0; m < 4; m++) {
#pragma unroll
        for (int n = 0; n < 4; n++) {
            const int col = v0 + wcol * 64 + n * 16 + l15;
            const int row = b0 + wrow * 64 + m * 16 + hi * 4;
#pragma unroll
            for (int r = 0; r < 4; r++)
                P[(size_t)(row + r) * 1024 + col] = __float2bfloat16(acc[m][n][r]);
        }
    }
#undef BARRIER
#undef WAITV
#undef WAITL0
}

// ---------------- elementwise LSTM epilogue, 8-wide (+ prev tail + step) --------
__global__ __launch_bounds__(256) void epilogue3(
    const __hip_bfloat16* __restrict__ pre,  // [5][2048][1024] bf16
    const float* __restrict__ c_tm1, const float* __restrict__ bias,
    const float* __restrict__ bias2, const float* __restrict__ s0p,
    const float* __restrict__ step, float* __restrict__ out_h,
    float* __restrict__ out_ht, float* __restrict__ out_c,
    float* __restrict__ out_step, float* __restrict__ out_prev, int write_tail) {
    const int idx = blockIdx.x * 256 + threadIdx.x;  // (b, v8): 2048 x 128
    const int b = idx >> 7;
    const int v = (idx & 127) * 8;
    const size_t bv = (size_t)b * 1024 + v;

    union u8 { short8 s; unsigned short u[8]; };
    u8 pi, pf, pc, po, ps;
    pi.s = *(const short8*)(pre + bv);
    pf.s = *(const short8*)(pre + 2097152 + bv);
    pc.s = *(const short8*)(pre + 4194304 + bv);
    po.s = *(const short8*)(pre + 6291456 + bv);
    ps.s = *(const short8*)(pre + 8388608 + bv);
    const float s0 = s0p[0];

    float hv[8], iv8[8], fv8[8], cn8[8], ov8[8];
#pragma unroll
    for (int j = 0; j < 4; j++) {
        // process two float4 groups j-range below; unified 8-loop:
    }
#pragma unroll
    for (int j = 0; j < 8; j++) {
        const float pif = __bfloat162float(*(const __hip_bfloat16*)&pi.u[j]) + bias[v + j];
        const float pff = __bfloat162float(*(const __hip_bfloat16*)&pf.u[j]) + bias[1024 + v + j];
        const float pcf = __bfloat162float(*(const __hip_bfloat16*)&pc.u[j]) + bias[2048 + v + j];
        const float pof = __bfloat162float(*(const __hip_bfloat16*)&po.u[j]) + bias[3072 + v + j];
        const float psf = __bfloat162float(*(const __hip_bfloat16*)&ps.u[j]) + bias2[v + j];
        const float ct = c_tm1[bv + j];
        const float iv = sigmoidf_(pif);
        const float fv = sigmoidf_(pff);
        const float cn = fv * ct + iv * tanhf(pcf);
        const float ov = sigmoidf_(pof);
        const float sk = sigmoidf_(psf);
        hv[j] = s0 * (ov * tanhf(cn)) + sk * (1.0f - s0);
        iv8[j] = iv; fv8[j] = fv; cn8[j] = cn; ov8[j] = ov;
    }
#pragma unroll
    for (int q = 0; q < 2; q++) {
        const int o = q * 4;
        *(float4*)(out_h + bv + o) = make_float4(hv[o], hv[o+1], hv[o+2], hv[o+3]);
        *(float4*)(out_c + bv + o) = make_float4(cn8[o], cn8[o+1], cn8[o+2], cn8[o+3]);
        float* ht = out_ht + (size_t)b * 4096 + v + o;
        *(float4*)(ht) = make_float4(iv8[o], iv8[o+1], iv8[o+2], iv8[o+3]);
        *(float4*)(ht + 1024) = make_float4(fv8[o], fv8[o+1], fv8[o+2], fv8[o+3]);
        *(float4*)(ht + 2048) = make_float4(cn8[o], cn8[o+1], cn8[o+2], cn8[o+3]);
        *(float4*)(ht + 3072) = make_float4(ov8[o], ov8[o+1], ov8[o+2], ov8[o+3]);
        if (write_tail)
            *(float4*)(out_prev + (size_t)b * 24576 + 23552 + v + o) =
                make_float4(hv[o], hv[o+1], hv[o+2], hv[o+3]);
    }
    if (idx < 2048) out_step[idx] = step[idx] + 1.0f;
}

// ---------------- fallback shift (scratch aliased in out_prev) -------------------
__global__ __launch_bounds__(256) void shift_only(
    const float* __restrict__ prev_h, const float* __restrict__ out_h,
    float* __restrict__ out_prev) {
    const int b = blockIdx.x;  // 0..2047
    float4* d = (float4*)(out_prev + (size_t)b * 24576);
    const float4* s1 = (const float4*)(prev_h + (size_t)b * 24576 + 1024);
    const float4* s2 = (const float4*)(out_h + (size_t)b * 1024);
    for (int c = threadIdx.x; c < 6144; c += 256)
        d[c] = (c < 5888) ? s1[c] : s2[c - 5888];
}

extern "C" void kernel_launch(void* const* d_in, const int* in_sizes, int n_in,
                              void* d_out, int out_size, void* d_ws, size_t ws_size,
                              hipStream_t stream) {
    (void)in_sizes; (void)n_in; (void)out_size;
    const float* inputs = (const float*)d_in[0];
    const float* h_tm1 = (const float*)d_in[1];
    const float* c_tm1 = (const float*)d_in[2];
    const float* step = (const float*)d_in[3];
    const float* prev_h = (const float*)d_in[4];
    const float* kernel = (const float*)d_in[5];
    const float* rkernel = (const float*)d_in[6];
    const float* kernel2 = (const float*)d_in[7];
    const float* bias = (const float*)d_in[8];
    const float* bias2 = (const float*)d_in[9];
    const float* s0 = (const float*)d_in[10];

    float* out = (float*)d_out;
    float* out_h = out;                // [B,U]
    float* out_ht = out + 2097152;     // [B,4U]
    float* out_c = out + 10485760;     // [B,U]
    float* out_step = out + 12582912;  // [B,1]
    float* out_prev = out + 12584960;  // [B,U*SKIP]

    const size_t NEED = 44040192 + 20971520;  // 42MB bf16 scratch + 20MB bf16 pre
    const int fits = (ws_size >= NEED);
    char* scr = fits ? (char*)d_ws : (char*)out_prev;
    __hip_bfloat16* kt = (__hip_bfloat16*)(scr + 0);           // [4096][1024]
    __hip_bfloat16* rkt = (__hip_bfloat16*)(scr + 8388608);    // [4096][1024]
    __hip_bfloat16* k2t = (__hip_bfloat16*)(scr + 16777216);   // [1024][1024]
    __hip_bfloat16* xin = (__hip_bfloat16*)(scr + 18874368);   // [2048][1024]
    __hip_bfloat16* hb = (__hip_bfloat16*)(scr + 23068672);    // [2048][4096]
    __hip_bfloat16* ph0 = (__hip_bfloat16*)(scr + 39845888);   // [2048][1024]
    __hip_bfloat16* pre = (__hip_bfloat16*)(scr + 44040192);   // [5][2048][1024]

    prep<<<21504, 256, 0, stream>>>(inputs, h_tm1, prev_h, kernel, rkernel, kernel2,
                                    kt, rkt, k2t, xin, hb, ph0);
    if (fits) {
        mega5<<<2688, 256, 0, stream>>>(xin, hb, ph0, kt, rkt, k2t, prev_h, out_prev, pre);
        epilogue3<<<1024, 256, 0, stream>>>(pre, c_tm1, bias, bias2, s0, step,
                                            out_h, out_ht, out_c, out_step, out_prev, 1);
    } else {
        mega5<<<640, 256, 0, stream>>>(xin, hb, ph0, kt, rkt, k2t, prev_h, out_prev, pre);
        epilogue3<<<1024, 256, 0, stream>>>(pre, c_tm1, bias, bias2, s0, step,
                                            out_h, out_ht, out_c, out_step, out_prev, 0);
        shift_only<<<2048, 256, 0, stream>>>(prev_h, out_h, out_prev);
    }
}